// Round 4
// baseline (556.095 us; speedup 1.0000x reference)
//
#include <hip/hip_runtime.h>
#include <math.h>

#define BATCH 32768
#define LW    200
#define CIN   6
#define KSZ   5
#define FLAT  196     // LW - KSZ + 1
#define NH1   50
#define NH2   30
#define NOUT  15

// One fused kernel: conv1d + fc1 (split-K across the block's 4 waves) +
// fc2 + fc3 + Procrustes (f32 Jacobi on the Davenport K-matrix).
//
// Block = 256 threads = 4 waves; 64 batches per block (batch = lane).
// Wave w owns conv outputs [KST[w], KST[w]+NCH[w]*4) (52/48/48/48 = 196),
// computes them from x with a rolling float4 window (+1-chunk prefetch),
// and immediately accumulates fc1 partials. w1 row indices are wave-uniform
// -> scalar loads (broadcast). Partials meet in LDS; wave 0 runs the tail.
__global__ __launch_bounds__(256) void fused_kernel(
    const float* __restrict__ x,
    const float* __restrict__ cw, const float* __restrict__ cb,
    const float* __restrict__ w1, const float* __restrict__ b1,
    const float* __restrict__ w2, const float* __restrict__ b2,
    const float* __restrict__ w3, const float* __restrict__ b3,
    float* __restrict__ out)
{
    __shared__ float part[3][64][53];   // waves 1..3 partials; 53: odd stride -> no bank conflicts

    const int tid  = threadIdx.x;
    const int wv   = __builtin_amdgcn_readfirstlane(tid >> 6);  // wave id (SGPR)
    const int lane = tid & 63;
    const int b    = blockIdx.x * 64 + lane;

    // K-slice per wave: starts are multiples of 4 floats with 16B-aligned byte
    // offsets (52*4=208, 100*4=400, 148*4=592 all %16==0).
    const int KST[4] = {0, 52, 100, 148};
    const int kstart = KST[wv];
    const int nchunk = (wv == 0) ? 13 : 12;   // chunks of 4 conv outputs

    // conv weights / bias: uniform -> scalar regs
    float w[CIN][KSZ];
#pragma unroll
    for (int c = 0; c < CIN; ++c)
#pragma unroll
        for (int k = 0; k < KSZ; ++k) w[c][k] = cw[c * KSZ + k];
    const float bias = cb[0];

    float h1p[NH1];
#pragma unroll
    for (int j = 0; j < NH1; ++j) h1p[j] = 0.f;

    // rolling window: chunk c needs x4[c] (cur) and x4[c+1] (nxt), relative
    // to this wave's kstart. fut prefetches x4[c+2] one chunk ahead.
    const float* xb = x + (size_t)b * (CIN * LW) + kstart;
    float4 cur[CIN], nxt[CIN];
#pragma unroll
    for (int c = 0; c < CIN; ++c) {
        cur[c] = *(const float4*)(xb + c * LW);
        nxt[c] = *(const float4*)(xb + c * LW + 4);
    }

    for (int c = 0; c < nchunk; ++c) {
        int pf = c + 2; if (pf > nchunk) pf = nchunk;   // clamp: stay in-row
        float4 fut[CIN];
#pragma unroll
        for (int ch = 0; ch < CIN; ++ch)
            fut[ch] = *(const float4*)(xb + ch * LW + 4 * pf);

        // conv: 4 outputs o = kstart+4c+r from window floats [4c .. 4c+8)
        float a0 = bias, a1 = bias, a2 = bias, a3 = bias;
#pragma unroll
        for (int ch = 0; ch < CIN; ++ch) {
            float xf[8] = {cur[ch].x, cur[ch].y, cur[ch].z, cur[ch].w,
                           nxt[ch].x, nxt[ch].y, nxt[ch].z, nxt[ch].w};
#pragma unroll
            for (int k = 0; k < KSZ; ++k) {
                a0 = fmaf(xf[k + 0], w[ch][k], a0);
                a1 = fmaf(xf[k + 1], w[ch][k], a1);
                a2 = fmaf(xf[k + 2], w[ch][k], a2);
                a3 = fmaf(xf[k + 3], w[ch][k], a3);
            }
        }

        // fc1 partial: rows kstart+4c .. +3 of w1 (wave-uniform -> s_load)
        const float* wrow = w1 + (size_t)(kstart + 4 * c) * NH1;
#pragma unroll
        for (int j = 0; j < NH1; ++j) h1p[j] = fmaf(a0, wrow[j], h1p[j]);
#pragma unroll
        for (int j = 0; j < NH1; ++j) h1p[j] = fmaf(a1, wrow[NH1 + j], h1p[j]);
#pragma unroll
        for (int j = 0; j < NH1; ++j) h1p[j] = fmaf(a2, wrow[2 * NH1 + j], h1p[j]);
#pragma unroll
        for (int j = 0; j < NH1; ++j) h1p[j] = fmaf(a3, wrow[3 * NH1 + j], h1p[j]);

#pragma unroll
        for (int ch = 0; ch < CIN; ++ch) { cur[ch] = nxt[ch]; nxt[ch] = fut[ch]; }
    }

    if (wv != 0) {
#pragma unroll
        for (int j = 0; j < NH1; ++j) part[wv - 1][lane][j] = h1p[j];
    }
    __syncthreads();
    if (wv != 0) return;   // free these SIMD slots for the co-resident block

    // ---- tail on wave 0: reduce + bias + relu ----
    float h1[NH1];
#pragma unroll
    for (int j = 0; j < NH1; ++j) {
        float s = h1p[j] + part[0][lane][j] + part[1][lane][j] + part[2][lane][j] + b1[j];
        h1[j] = fmaxf(s, 0.f);
    }

    // fc2
    float h2[NH2];
#pragma unroll
    for (int j = 0; j < NH2; ++j) h2[j] = b2[j];
#pragma unroll
    for (int k = 0; k < NH1; ++k) {
        float hk = h1[k];
        const float* row = w2 + k * NH2;              // uniform -> s_load
#pragma unroll
        for (int j = 0; j < NH2; ++j) h2[j] = fmaf(hk, row[j], h2[j]);
    }
#pragma unroll
    for (int j = 0; j < NH2; ++j) h2[j] = fmaxf(h2[j], 0.f);

    // fc3 (no relu)
    float o[NOUT];
#pragma unroll
    for (int j = 0; j < NOUT; ++j) o[j] = b3[j];
#pragma unroll
    for (int k = 0; k < NH2; ++k) {
        float hk = h2[k];
        const float* row = w3 + k * NOUT;             // uniform -> s_load
#pragma unroll
        for (int j = 0; j < NOUT; ++j) o[j] = fmaf(hk, row[j], o[j]);
    }

    // ---- closest proper rotation (Davenport K-matrix, f32 Jacobi) ----
    {
        float r00 = o[0], r01 = o[1], r02 = o[2];
        float r10 = o[3], r11 = o[4], r12 = o[5];
        float r20 = o[6], r21 = o[7], r22 = o[8];

        float A[4][4], V[4][4];
        A[0][0] = r00 + r11 + r22;
        A[1][1] = r00 - r11 - r22;
        A[2][2] = r11 - r00 - r22;
        A[3][3] = r22 - r00 - r11;
        A[0][1] = A[1][0] = r21 - r12;
        A[0][2] = A[2][0] = r02 - r20;
        A[0][3] = A[3][0] = r10 - r01;
        A[1][2] = A[2][1] = r01 + r10;
        A[1][3] = A[3][1] = r02 + r20;
        A[2][3] = A[3][2] = r12 + r21;
#pragma unroll
        for (int i = 0; i < 4; ++i)
#pragma unroll
            for (int j = 0; j < 4; ++j) V[i][j] = (i == j) ? 1.f : 0.f;

        const int pr[6][2] = {{0,1},{0,2},{0,3},{1,2},{1,3},{2,3}};
        for (int sweep = 0; sweep < 7; ++sweep) {
#pragma unroll
            for (int pi = 0; pi < 6; ++pi) {
                const int p = pr[pi][0], q = pr[pi][1];
                float apq = A[p][q];
                if (fabsf(apq) > 1e-20f) {
                    float theta = (A[q][q] - A[p][p]) / (2.f * apq);
                    float t = copysignf(1.f, theta) / (fabsf(theta) + sqrtf(1.f + theta * theta));
                    float c = rsqrtf(1.f + t * t);
                    float s = t * c;
#pragma unroll
                    for (int k = 0; k < 4; ++k) {
                        float akp = A[k][p], akq = A[k][q];
                        A[k][p] = c * akp - s * akq;
                        A[k][q] = s * akp + c * akq;
                    }
#pragma unroll
                    for (int k = 0; k < 4; ++k) {
                        float apk = A[p][k], aqk = A[q][k];
                        A[p][k] = c * apk - s * aqk;
                        A[q][k] = s * apk + c * aqk;
                    }
#pragma unroll
                    for (int k = 0; k < 4; ++k) {
                        float vkp = V[k][p], vkq = V[k][q];
                        V[k][p] = c * vkp - s * vkq;
                        V[k][q] = s * vkp + c * vkq;
                    }
                }
            }
        }

        int best = 0;
        float bl = A[0][0];
#pragma unroll
        for (int i = 1; i < 4; ++i)
            if (A[i][i] > bl) { bl = A[i][i]; best = i; }

        float vw = V[0][best], vx = V[1][best], vy = V[2][best], vz = V[3][best];
        float inv = rsqrtf(vw * vw + vx * vx + vy * vy + vz * vz);
        vw *= inv; vx *= inv; vy *= inv; vz *= inv;

        float xx = vx * vx, yy = vy * vy, zz = vz * vz;
        float xy = vx * vy, xz = vx * vz, yz = vy * vz;
        float wx = vw * vx, wy = vw * vy, wz = vw * vz;

        float* ob = out + (long)b * NOUT;
        ob[0]  = 1.f - 2.f * (yy + zz);
        ob[1]  = 2.f * (xy - wz);
        ob[2]  = 2.f * (xz + wy);
        ob[3]  = 2.f * (xy + wz);
        ob[4]  = 1.f - 2.f * (xx + zz);
        ob[5]  = 2.f * (yz - wx);
        ob[6]  = 2.f * (xz - wy);
        ob[7]  = 2.f * (yz + wx);
        ob[8]  = 1.f - 2.f * (xx + yy);
        ob[9]  = o[9];
        ob[10] = o[10];
        ob[11] = o[11];
        ob[12] = o[12];
        ob[13] = o[13];
        ob[14] = o[14];
    }
}

extern "C" void kernel_launch(void* const* d_in, const int* in_sizes, int n_in,
                              void* d_out, int out_size, void* d_ws, size_t ws_size,
                              hipStream_t stream) {
    const float* x  = (const float*)d_in[0];
    const float* cw = (const float*)d_in[1];
    const float* cb = (const float*)d_in[2];
    const float* w1 = (const float*)d_in[3];
    const float* b1 = (const float*)d_in[4];
    const float* w2 = (const float*)d_in[5];
    const float* b2 = (const float*)d_in[6];
    const float* w3 = (const float*)d_in[7];
    const float* b3 = (const float*)d_in[8];
    float* outp = (float*)d_out;

    fused_kernel<<<BATCH / 64, 256, 0, stream>>>(x, cw, cb, w1, b1, w2, b2, w3, b3, outp);
}

// Round 5
// 314.206 us; speedup vs baseline: 1.7698x; 1.7698x over previous
//
#include <hip/hip_runtime.h>
#include <math.h>

#define BATCH 32768
#define LW    200
#define CIN   6
#define KSZ   5
#define FLAT  196     // LW - KSZ + 1
#define NH1   50
#define NH2   30
#define NOUT  15
#define ROWP  201     // LDS row stride (odd -> conflict-free column reads)

// Fused conv1d + fc1 (split-K over 4 waves) + fc2/fc3 + Procrustes.
// Key fix vs round 4: x is staged into LDS with COALESCED global reads
// (lanes along the L dimension), then read batch-per-lane from LDS for the
// conv. This removes the 8x cache-line over-fetch (1.25 GB -> ~160 MB).
__global__ __launch_bounds__(256) void fused_kernel(
    const float* __restrict__ x,
    const float* __restrict__ cw, const float* __restrict__ cb,
    const float* __restrict__ w1, const float* __restrict__ b1,
    const float* __restrict__ w2, const float* __restrict__ b2,
    const float* __restrict__ w3, const float* __restrict__ b3,
    float* __restrict__ out)
{
    __shared__ float xs[64 * ROWP];   // 51.5 KB; 3 blocks/CU -> 12 waves/CU

    const int tid  = threadIdx.x;
    const int wv   = __builtin_amdgcn_readfirstlane(tid >> 6);  // SGPR wave id
    const int lane = tid & 63;
    const int b    = blockIdx.x * 64 + lane;
    const int kstart = 49 * wv;       // this wave's conv-output slice [kstart, kstart+49)

    // conv weights / bias: uniform -> scalar regs
    float w[CIN][KSZ];
#pragma unroll
    for (int c = 0; c < CIN; ++c)
#pragma unroll
        for (int k = 0; k < KSZ; ++k) w[c][k] = cw[c * KSZ + k];

    // staging thread constants: thread t covers linear floats l = t + 256k,
    // k = 0..49 (exactly 64*200 = 12800 = 256*50). l -> (bb = l/200, i = l%200).
    const int bb0 = (tid >= 200) ? 1 : 0;
    const int i0  = tid - 200 * bb0;
    const float* xblk = x + (size_t)blockIdx.x * 64 * (CIN * LW);

    float acc[49];
    const float bias = cb[0];
#pragma unroll
    for (int i = 0; i < 49; ++i) acc[i] = bias;

    for (int ch = 0; ch < CIN; ++ch) {
        __syncthreads();   // previous channel's conv reads done before overwrite

        // ---- stage channel ch: coalesced global -> LDS transpose ----
        {
            int i  = i0;
            int go = bb0 * (CIN * LW) + ch * LW + i0;   // global float offset in block slab
            int lo = bb0 * ROWP + i0;                   // LDS float offset
            for (int kb = 0; kb < 5; ++kb) {
                float v[10]; int lof[10];
#pragma unroll
                for (int u = 0; u < 10; ++u) {
                    v[u] = xblk[go];
                    lof[u] = lo;
                    // advance l by 256: i+56 (bb+1) or i-144 (bb+2)
                    bool two = (i >= 144);
                    i  += two ? -144 : 56;
                    go += two ? 2 * (CIN * LW) - 144 : (CIN * LW) + 56;
                    lo += two ? 2 * ROWP - 144 : ROWP + 56;
                }
#pragma unroll
                for (int u = 0; u < 10; ++u) xs[lof[u]] = v[u];
            }
        }
        __syncthreads();

        // ---- conv accumulate for this wave's slice (batch = lane) ----
        // row reads: addr = lane*201 + ..., 201 odd -> conflict-free (2-way).
        const float* row = xs + lane * ROWP + kstart;
        float x0 = row[0], x1 = row[1], x2 = row[2], x3 = row[3];
#pragma unroll
        for (int i = 0; i < 49; ++i) {
            float x4v = row[i + 4];
            float a = acc[i];
            a = fmaf(x0, w[ch][0], a);
            a = fmaf(x1, w[ch][1], a);
            a = fmaf(x2, w[ch][2], a);
            a = fmaf(x3, w[ch][3], a);
            a = fmaf(x4v, w[ch][4], a);
            acc[i] = a;
            x0 = x1; x1 = x2; x2 = x3; x3 = x4v;
        }
    }

    // ---- fc1 partials: rows kstart..kstart+48 of w1 (wave-uniform -> s_load) ----
    float h1p[NH1];
#pragma unroll
    for (int j = 0; j < NH1; ++j) h1p[j] = 0.f;
#pragma unroll
    for (int ii = 0; ii < 49; ++ii) {
        const float* wrow = w1 + (size_t)(kstart + ii) * NH1;
        float c = acc[ii];
#pragma unroll
        for (int j = 0; j < NH1; ++j) h1p[j] = fmaf(c, wrow[j], h1p[j]);
    }

    // ---- cross-wave reduction through LDS (reuse xs; 3*64*53 <= 64*201) ----
    __syncthreads();   // conv reads of last channel done before reuse
    float* part = xs;
    if (wv != 0) {
#pragma unroll
        for (int j = 0; j < NH1; ++j)
            part[(size_t)(wv - 1) * (64 * 53) + lane * 53 + j] = h1p[j];
    }
    __syncthreads();
    if (wv != 0) return;   // free SIMD slots; wave 0 runs the tail

    float h1[NH1];
#pragma unroll
    for (int j = 0; j < NH1; ++j) {
        float s = h1p[j]
                + part[lane * 53 + j]
                + part[64 * 53 + lane * 53 + j]
                + part[2 * 64 * 53 + lane * 53 + j]
                + b1[j];
        h1[j] = fmaxf(s, 0.f);
    }

    // fc2
    float h2[NH2];
#pragma unroll
    for (int j = 0; j < NH2; ++j) h2[j] = b2[j];
#pragma unroll
    for (int k = 0; k < NH1; ++k) {
        float hk = h1[k];
        const float* row = w2 + k * NH2;              // uniform -> s_load
#pragma unroll
        for (int j = 0; j < NH2; ++j) h2[j] = fmaf(hk, row[j], h2[j]);
    }
#pragma unroll
    for (int j = 0; j < NH2; ++j) h2[j] = fmaxf(h2[j], 0.f);

    // fc3 (no relu)
    float o[NOUT];
#pragma unroll
    for (int j = 0; j < NOUT; ++j) o[j] = b3[j];
#pragma unroll
    for (int k = 0; k < NH2; ++k) {
        float hk = h2[k];
        const float* row = w3 + k * NOUT;             // uniform -> s_load
#pragma unroll
        for (int j = 0; j < NOUT; ++j) o[j] = fmaf(hk, row[j], o[j]);
    }

    // ---- closest proper rotation (Davenport K-matrix, f32 Jacobi) ----
    {
        float r00 = o[0], r01 = o[1], r02 = o[2];
        float r10 = o[3], r11 = o[4], r12 = o[5];
        float r20 = o[6], r21 = o[7], r22 = o[8];

        float A[4][4], V[4][4];
        A[0][0] = r00 + r11 + r22;
        A[1][1] = r00 - r11 - r22;
        A[2][2] = r11 - r00 - r22;
        A[3][3] = r22 - r00 - r11;
        A[0][1] = A[1][0] = r21 - r12;
        A[0][2] = A[2][0] = r02 - r20;
        A[0][3] = A[3][0] = r10 - r01;
        A[1][2] = A[2][1] = r01 + r10;
        A[1][3] = A[3][1] = r02 + r20;
        A[2][3] = A[3][2] = r12 + r21;
#pragma unroll
        for (int i = 0; i < 4; ++i)
#pragma unroll
            for (int j = 0; j < 4; ++j) V[i][j] = (i == j) ? 1.f : 0.f;

        const int pr[6][2] = {{0,1},{0,2},{0,3},{1,2},{1,3},{2,3}};
        for (int sweep = 0; sweep < 7; ++sweep) {
#pragma unroll
            for (int pi = 0; pi < 6; ++pi) {
                const int p = pr[pi][0], q = pr[pi][1];
                float apq = A[p][q];
                if (fabsf(apq) > 1e-20f) {
                    float theta = (A[q][q] - A[p][p]) / (2.f * apq);
                    float t = copysignf(1.f, theta) / (fabsf(theta) + sqrtf(1.f + theta * theta));
                    float c = rsqrtf(1.f + t * t);
                    float s = t * c;
#pragma unroll
                    for (int k = 0; k < 4; ++k) {
                        float akp = A[k][p], akq = A[k][q];
                        A[k][p] = c * akp - s * akq;
                        A[k][q] = s * akp + c * akq;
                    }
#pragma unroll
                    for (int k = 0; k < 4; ++k) {
                        float apk = A[p][k], aqk = A[q][k];
                        A[p][k] = c * apk - s * aqk;
                        A[q][k] = s * apk + c * aqk;
                    }
#pragma unroll
                    for (int k = 0; k < 4; ++k) {
                        float vkp = V[k][p], vkq = V[k][q];
                        V[k][p] = c * vkp - s * vkq;
                        V[k][q] = s * vkp + c * vkq;
                    }
                }
            }
        }

        int best = 0;
        float bl = A[0][0];
#pragma unroll
        for (int i = 1; i < 4; ++i)
            if (A[i][i] > bl) { bl = A[i][i]; best = i; }

        float vw = V[0][best], vx = V[1][best], vy = V[2][best], vz = V[3][best];
        float inv = rsqrtf(vw * vw + vx * vx + vy * vy + vz * vz);
        vw *= inv; vx *= inv; vy *= inv; vz *= inv;

        float xx = vx * vx, yy = vy * vy, zz = vz * vz;
        float xy = vx * vy, xz = vx * vz, yz = vy * vz;
        float wx = vw * vx, wy = vw * vy, wz = vw * vz;

        float* ob = out + (long)b * NOUT;
        ob[0]  = 1.f - 2.f * (yy + zz);
        ob[1]  = 2.f * (xy - wz);
        ob[2]  = 2.f * (xz + wy);
        ob[3]  = 2.f * (xy + wz);
        ob[4]  = 1.f - 2.f * (xx + zz);
        ob[5]  = 2.f * (yz - wx);
        ob[6]  = 2.f * (xz - wy);
        ob[7]  = 2.f * (yz + wx);
        ob[8]  = 1.f - 2.f * (xx + yy);
        ob[9]  = o[9];
        ob[10] = o[10];
        ob[11] = o[11];
        ob[12] = o[12];
        ob[13] = o[13];
        ob[14] = o[14];
    }
}

extern "C" void kernel_launch(void* const* d_in, const int* in_sizes, int n_in,
                              void* d_out, int out_size, void* d_ws, size_t ws_size,
                              hipStream_t stream) {
    const float* x  = (const float*)d_in[0];
    const float* cw = (const float*)d_in[1];
    const float* cb = (const float*)d_in[2];
    const float* w1 = (const float*)d_in[3];
    const float* b1 = (const float*)d_in[4];
    const float* w2 = (const float*)d_in[5];
    const float* b2 = (const float*)d_in[6];
    const float* w3 = (const float*)d_in[7];
    const float* b3 = (const float*)d_in[8];
    float* outp = (float*)d_out;

    fused_kernel<<<BATCH / 64, 256, 0, stream>>>(x, cw, cb, w1, b1, w2, b2, w3, b3, outp);
}

// Round 6
// 298.241 us; speedup vs baseline: 1.8646x; 1.0535x over previous
//
#include <hip/hip_runtime.h>
#include <math.h>

#define BATCH 32768
#define LW    200
#define CIN   6
#define KSZ   5
#define FLAT  196     // LW - KSZ + 1
#define NH1   50
#define NH2   30
#define NOUT  15
#define TILEW 57      // LDS tile row stride (floats); odd -> conflict-free lane*TILEW reads
#define NLD   14      // float4 loads per lane per channel (64*56/4/64)

// Fused conv1d + fc1 + fc2/fc3 + Procrustes.
// Round-6 structure: WAVE-AUTONOMOUS staging. Each wave owns a private LDS
// slab [64 batches][56 cols] covering global cols [48*wv, 48*wv+56) of one
// channel. Staging loads are 14 independent dwordx4 per lane (descriptors
// precomputed -> no serial address chain); the write->read dependency is
// wave-internal (in-order LDS), so the 6-channel main loop has ZERO block
// barriers. Loads for ch+1 issue before the conv of ch (latency hidden).
// Conv output slice per wave: [49*wv, 49*wv+49) (window offset = wv in tile).
__global__ __launch_bounds__(256) void fused_kernel(
    const float* __restrict__ x,
    const float* __restrict__ cw, const float* __restrict__ cb,
    const float* __restrict__ w1, const float* __restrict__ b1,
    const float* __restrict__ w2, const float* __restrict__ b2,
    const float* __restrict__ w3, const float* __restrict__ b3,
    float* __restrict__ out)
{
    __shared__ float xs[4 * 64 * TILEW];   // 58368 B -> 2 blocks/CU

    const int tid  = threadIdx.x;
    const int wv   = __builtin_amdgcn_readfirstlane(tid >> 6);  // SGPR wave id
    const int lane = tid & 63;
    const int b    = blockIdx.x * 64 + lane;
    const int kstart = 49 * wv;            // conv-output slice [kstart, kstart+49)
    const int tbase  = 48 * wv;            // tile's global-col base (16B aligned)
    const int off    = wv;                 // kstart - tbase, window offset in tile

    float* tile = xs + wv * (64 * TILEW);  // this wave's private slab

    // conv weights / bias: uniform -> scalar regs
    float w[CIN][KSZ];
#pragma unroll
    for (int c = 0; c < CIN; ++c)
#pragma unroll
        for (int k = 0; k < KSZ; ++k) w[c][k] = cw[c * KSZ + k];
    const float bias = cb[0];

    // staging descriptors: float4 #g = lane + 64u of the [64 rows][14 f4] tile
    int goff[NLD];   // global float offset (relative to block slab + tbase, ch=0)
    int loff[NLD];   // LDS float offset within tile
#pragma unroll
    for (int u = 0; u < NLD; ++u) {
        int g   = lane + 64 * u;
        int row = g / NLD;
        int c4  = g - row * NLD;
        goff[u] = row * (CIN * LW) + 4 * c4;
        loff[u] = row * TILEW + 4 * c4;
    }
    const float* xw = x + (size_t)blockIdx.x * 64 * (CIN * LW) + tbase;

    float acc[49];
#pragma unroll
    for (int i = 0; i < 49; ++i) acc[i] = bias;

    // prologue: issue channel 0 loads (14 independent dwordx4)
    float4 buf[NLD];
#pragma unroll
    for (int u = 0; u < NLD; ++u)
        buf[u] = *(const float4*)(xw + goff[u]);

#pragma unroll
    for (int ch = 0; ch < CIN; ++ch) {
        // drain buf -> LDS (scalar writes; ~2-way banks = free)
#pragma unroll
        for (int u = 0; u < NLD; ++u) {
            float* dst = tile + loff[u];
            dst[0] = buf[u].x; dst[1] = buf[u].y; dst[2] = buf[u].z; dst[3] = buf[u].w;
        }
        // issue next channel's loads before consuming this one (hide latency)
        if (ch + 1 < CIN) {
#pragma unroll
            for (int u = 0; u < NLD; ++u)
                buf[u] = *(const float4*)(xw + (ch + 1) * LW + goff[u]);
        }
        // conv accumulate (batch = lane); stride TILEW=57 odd -> conflict-free
        const float* row = tile + lane * TILEW + off;
        float x0 = row[0], x1 = row[1], x2 = row[2], x3 = row[3];
#pragma unroll
        for (int i = 0; i < 49; ++i) {
            float x4v = row[i + 4];
            float a = acc[i];
            a = fmaf(x0, w[ch][0], a);
            a = fmaf(x1, w[ch][1], a);
            a = fmaf(x2, w[ch][2], a);
            a = fmaf(x3, w[ch][3], a);
            a = fmaf(x4v, w[ch][4], a);
            acc[i] = a;
            x0 = x1; x1 = x2; x2 = x3; x3 = x4v;
        }
    }

    // ---- fc1 partials: rows kstart..kstart+48 of w1 (wave-uniform -> s_load) ----
    float h1p[NH1];
#pragma unroll
    for (int j = 0; j < NH1; ++j) h1p[j] = 0.f;
#pragma unroll
    for (int ii = 0; ii < 49; ++ii) {
        const float* wrow = w1 + (size_t)(kstart + ii) * NH1;
        float c = acc[ii];
#pragma unroll
        for (int j = 0; j < NH1; ++j) h1p[j] = fmaf(c, wrow[j], h1p[j]);
    }

    // ---- cross-wave reduction (the only block barriers) ----
    __syncthreads();   // all tiles dead; safe to reuse xs
    float* part = xs;  // [3][64][53] = 10176 floats <= 14592
    if (wv != 0) {
#pragma unroll
        for (int j = 0; j < NH1; ++j)
            part[(wv - 1) * (64 * 53) + lane * 53 + j] = h1p[j];
    }
    __syncthreads();
    if (wv != 0) return;   // free SIMD slots; wave 0 runs the tail

    float h1[NH1];
#pragma unroll
    for (int j = 0; j < NH1; ++j) {
        float s = h1p[j]
                + part[lane * 53 + j]
                + part[64 * 53 + lane * 53 + j]
                + part[2 * 64 * 53 + lane * 53 + j]
                + b1[j];
        h1[j] = fmaxf(s, 0.f);
    }

    // fc2
    float h2[NH2];
#pragma unroll
    for (int j = 0; j < NH2; ++j) h2[j] = b2[j];
#pragma unroll
    for (int k = 0; k < NH1; ++k) {
        float hk = h1[k];
        const float* row = w2 + k * NH2;              // uniform -> s_load
#pragma unroll
        for (int j = 0; j < NH2; ++j) h2[j] = fmaf(hk, row[j], h2[j]);
    }
#pragma unroll
    for (int j = 0; j < NH2; ++j) h2[j] = fmaxf(h2[j], 0.f);

    // fc3 (no relu)
    float o[NOUT];
#pragma unroll
    for (int j = 0; j < NOUT; ++j) o[j] = b3[j];
#pragma unroll
    for (int k = 0; k < NH2; ++k) {
        float hk = h2[k];
        const float* row = w3 + k * NOUT;             // uniform -> s_load
#pragma unroll
        for (int j = 0; j < NOUT; ++j) o[j] = fmaf(hk, row[j], o[j]);
    }

    // ---- closest proper rotation (Davenport K-matrix, f32 Jacobi) ----
    {
        float r00 = o[0], r01 = o[1], r02 = o[2];
        float r10 = o[3], r11 = o[4], r12 = o[5];
        float r20 = o[6], r21 = o[7], r22 = o[8];

        float A[4][4], V[4][4];
        A[0][0] = r00 + r11 + r22;
        A[1][1] = r00 - r11 - r22;
        A[2][2] = r11 - r00 - r22;
        A[3][3] = r22 - r00 - r11;
        A[0][1] = A[1][0] = r21 - r12;
        A[0][2] = A[2][0] = r02 - r20;
        A[0][3] = A[3][0] = r10 - r01;
        A[1][2] = A[2][1] = r01 + r10;
        A[1][3] = A[3][1] = r02 + r20;
        A[2][3] = A[3][2] = r12 + r21;
#pragma unroll
        for (int i = 0; i < 4; ++i)
#pragma unroll
            for (int j = 0; j < 4; ++j) V[i][j] = (i == j) ? 1.f : 0.f;

        const int pr[6][2] = {{0,1},{0,2},{0,3},{1,2},{1,3},{2,3}};
        for (int sweep = 0; sweep < 7; ++sweep) {
#pragma unroll
            for (int pi = 0; pi < 6; ++pi) {
                const int p = pr[pi][0], q = pr[pi][1];
                float apq = A[p][q];
                if (fabsf(apq) > 1e-20f) {
                    float theta = (A[q][q] - A[p][p]) / (2.f * apq);
                    float t = copysignf(1.f, theta) / (fabsf(theta) + sqrtf(1.f + theta * theta));
                    float c = rsqrtf(1.f + t * t);
                    float s = t * c;
#pragma unroll
                    for (int k = 0; k < 4; ++k) {
                        float akp = A[k][p], akq = A[k][q];
                        A[k][p] = c * akp - s * akq;
                        A[k][q] = s * akp + c * akq;
                    }
#pragma unroll
                    for (int k = 0; k < 4; ++k) {
                        float apk = A[p][k], aqk = A[q][k];
                        A[p][k] = c * apk - s * aqk;
                        A[q][k] = s * apk + c * aqk;
                    }
#pragma unroll
                    for (int k = 0; k < 4; ++k) {
                        float vkp = V[k][p], vkq = V[k][q];
                        V[k][p] = c * vkp - s * vkq;
                        V[k][q] = s * vkp + c * vkq;
                    }
                }
            }
        }

        int best = 0;
        float bl = A[0][0];
#pragma unroll
        for (int i = 1; i < 4; ++i)
            if (A[i][i] > bl) { bl = A[i][i]; best = i; }

        float vw = V[0][best], vx = V[1][best], vy = V[2][best], vz = V[3][best];
        float inv = rsqrtf(vw * vw + vx * vx + vy * vy + vz * vz);
        vw *= inv; vx *= inv; vy *= inv; vz *= inv;

        float xx = vx * vx, yy = vy * vy, zz = vz * vz;
        float xy = vx * vy, xz = vx * vz, yz = vy * vz;
        float wx = vw * vx, wy = vw * vy, wz = vw * vz;

        float* ob = out + (long)b * NOUT;
        ob[0]  = 1.f - 2.f * (yy + zz);
        ob[1]  = 2.f * (xy - wz);
        ob[2]  = 2.f * (xz + wy);
        ob[3]  = 2.f * (xy + wz);
        ob[4]  = 1.f - 2.f * (xx + zz);
        ob[5]  = 2.f * (yz - wx);
        ob[6]  = 2.f * (xz - wy);
        ob[7]  = 2.f * (yz + wx);
        ob[8]  = 1.f - 2.f * (xx + yy);
        ob[9]  = o[9];
        ob[10] = o[10];
        ob[11] = o[11];
        ob[12] = o[12];
        ob[13] = o[13];
        ob[14] = o[14];
    }
}

extern "C" void kernel_launch(void* const* d_in, const int* in_sizes, int n_in,
                              void* d_out, int out_size, void* d_ws, size_t ws_size,
                              hipStream_t stream) {
    const float* x  = (const float*)d_in[0];
    const float* cw = (const float*)d_in[1];
    const float* cb = (const float*)d_in[2];
    const float* w1 = (const float*)d_in[3];
    const float* b1 = (const float*)d_in[4];
    const float* w2 = (const float*)d_in[5];
    const float* b2 = (const float*)d_in[6];
    const float* w3 = (const float*)d_in[7];
    const float* b3 = (const float*)d_in[8];
    float* outp = (float*)d_out;

    fused_kernel<<<BATCH / 64, 256, 0, stream>>>(x, cw, cb, w1, b1, w2, b2, w3, b3, outp);
}